// Round 4
// baseline (230.533 us; speedup 1.0000x reference)
//
#include <hip/hip_runtime.h>

// Izhikevich spiking neuron scan — LDS-staged via global_load_lds DMA with
// hand-counted vmcnt waits and raw s_barrier (the guide's T3/T4 pattern).
//
// x: [T=512, N=65536] f32. out: [T, N] f32 spike train (0.0 / 1.0).
//
// Recurrence per neuron (bit-identical to all verified prior versions):
//   v = (4v^2 + 5v + 1.4 - r + x_t) * DT   (DT = 1/512)
//   r = 0.02 * (0.2v - v) * DT             (uses NEW v)
//   fire = v >= 0.3 ; fire -> v = -0.065, r += 0.008 ; out_t = fire
//
// Round-4: identical to round 3 except the vector type — HIP's float2 is a
// HIP_vector_type class, which __builtin_nontemporal_store rejects; use a
// clang ext_vector_type(2) alias (as rounds 1-2 did) everywhere.
//
// Round-3 theory (untested until now): two register-pipeline variants both
// plateaued at 2.5-2.8 TB/s — the compiler's automatic vmcnt insertion for
// register-destination loads serializes the pipeline (oldest-first counter
// polluted by stores; no source-level counted wait exists for register
// loads). Fix = the proven pattern: stage x through LDS with
// global_load_lds (no VGPR dest, no WAR hazards), double-buffered 4-step
// tiles, 2 tiles in flight, exact counted s_waitcnt vmcnt(N) + raw
// s_barrier (no compiler drain).
//
// vmcnt ledger (per wave; only stages [2/tile] and NT-stores [4/tile]
// touch vmcnt; ds_reads are lgkmcnt; all memory ops pinned by "memory"
// clobbers + sched_barrier so program order = issue order):
//   prologue: stage(0) 2, stage(1) 2
//   tile k:   waitK, bar, ds_read x4, lgkmcnt(0), bar, stage(k+2) 2,
//             compute + 4 stores
//   ops issued after stage(k) at tile k's wait:
//     k=0: stage1(2)                        -> vmcnt(2)
//     k=1: stage2(2)+stores0(4)             -> vmcnt(6)
//     k=2..6: stores(k-2)4+stage(k+1)2+stores(k-1)4 -> vmcnt(10)
//     k=7: stores5(4)+stores6(4)            -> vmcnt(8)
//
// Time-split justification (unchanged, verified absmax=0 three times): the
// map contracts prior state by ~(5/512)/step; 8 warmup steps shrink any
// init-state error below fp32 ulp.

#define T_STEPS 512
#define N_NEUR  65536
#define N2      (N_NEUR / 2)     // 32768 float2 columns
#define DT      (1.0f / 512.0f)
#define TCH     32               // timesteps per chunk (512/16 chunks)
#define WARM    8
#define NT      4                // timesteps per LDS tile
#define NTILES  (TCH / NT)       // 8 tiles per chunk
#define ROWB    2048             // bytes per timestep row per block (256 cols x 8B)
#define TILEB   (NT * ROWB)      // 8192 B per tile buffer

#define WAITVM(N) asm volatile("s_waitcnt vmcnt(" #N ")" ::: "memory")

typedef float v2f __attribute__((ext_vector_type(2)));

__device__ __forceinline__ void gll16(const void* g, void* l) {
    __builtin_amdgcn_global_load_lds(
        (const __attribute__((address_space(1))) void*)g,
        (__attribute__((address_space(3))) void*)l, 16, 0, 0);
}

__device__ __forceinline__ float izi_step(float xt, float& v, float& r) {
    v = (4.0f * v * v + 5.0f * v + 1.4f - r + xt) * DT;
    r = 0.02f * (0.2f * v - v) * DT;
    const bool fire = v >= 0.3f;
    if (fire) { v = -0.065f; r += 0.008f; }
    return fire ? 1.0f : 0.0f;
}

__device__ __forceinline__ v2f izi_step2(const v2f xt, v2f& v, v2f& r) {
    v2f o;
    float vx = v.x, rx = r.x, vy = v.y, ry = r.y;
    o.x = izi_step(xt.x, vx, rx);
    o.y = izi_step(xt.y, vy, ry);
    v.x = vx; r.x = rx; v.y = vy; r.y = ry;
    return o;
}

// Wave w stages timestep row (t) of the block: 2048 B = two 1 KB DMAs.
__device__ __forceinline__ void stage_row(const char* xrow, char* lrow, int lane) {
    gll16(xrow + lane * 16,        lrow);
    gll16(xrow + 1024 + lane * 16, lrow + 1024);
}

template <int K>
__device__ __forceinline__ void tile_body(const char* xb, char* smem, v2f* outp,
                                          int tid, int lane, int w, int tstart,
                                          v2f& v, v2f& r) {
    // 1. wait for this tile's DMA (own wave's ledger), then block barrier.
    if constexpr (K == 0)            WAITVM(2);
    else if constexpr (K == 1)       WAITVM(6);
    else if constexpr (K == NTILES - 1) WAITVM(8);
    else                             WAITVM(10);
    __builtin_amdgcn_s_barrier();          // all waves' DMA for tile K landed
    __builtin_amdgcn_sched_barrier(0);

    // 2. read this tile's 4 steps into registers (ds_read_b64, 2-way bank
    //    aliasing = free), then ensure reads completed before freeing buf.
    const v2f* sp = (const v2f*)(smem + (size_t)(K & 1) * TILEB);
    v2f xs[NT];
    #pragma unroll
    for (int i = 0; i < NT; ++i) xs[i] = sp[i * 256 + tid];
    asm volatile("s_waitcnt lgkmcnt(0)" ::: "memory");
    __builtin_amdgcn_s_barrier();          // all waves done reading buf[K&1]
    __builtin_amdgcn_sched_barrier(0);

    // 3. re-stage the freed buffer with tile K+2 (2 DMAs, fire-and-forget).
    if constexpr (K + 2 < NTILES) {
        const int t = tstart + (K + 2) * NT + w;
        stage_row(xb + (size_t)t * (N2 * 8), smem + (size_t)(K & 1) * TILEB + w * ROWB, lane);
    }

    // 4. recurrence + 4 non-temporal stores (output never re-read).
    #pragma unroll
    for (int i = 0; i < NT; ++i) {
        const v2f o = izi_step2(xs[i], v, r);
        __builtin_nontemporal_store(o, outp + (size_t)(tstart + K * NT + i) * N2);
    }
}

__global__ __launch_bounds__(256, 8) void izi_kernel(const v2f* __restrict__ x,
                                                     v2f* __restrict__ out) {
    __shared__ __align__(16) char smem[2 * TILEB];   // 16 KiB
    const int tid = threadIdx.x;
    const int lane = tid & 63;
    const int w = tid >> 6;                          // wave 0..3 stages row w
    const int bcol0 = blockIdx.x * 256;              // block's first float2 col
    const int c = blockIdx.y;                        // time chunk 0..15
    const int tstart = c * TCH;

    const char* xb = (const char*)x + (size_t)bcol0 * 8;  // block-col base
    v2f* outp = out + (size_t)bcol0 + tid;                // this thread's col

    v2f v; v.x = -0.065f; v.y = -0.065f;
    v2f r; r.x = 0.0f;    r.y = 0.0f;

    if (c > 0) {
        #pragma unroll
        for (int t = tstart - WARM; t < tstart; ++t) {
            const v2f xt = x[(size_t)t * N2 + bcol0 + tid];
            (void)izi_step2(xt, v, r);
        }
    }
    // Pin warmup (loads fully consumed -> vmcnt 0) before the DMA ledger starts.
    __builtin_amdgcn_sched_barrier(0);

    // Prologue: stage tiles 0 and 1 (wave w stages row w of each tile).
    stage_row(xb + (size_t)(tstart + 0 * NT + w) * (N2 * 8), smem + 0 * TILEB + w * ROWB, lane);
    stage_row(xb + (size_t)(tstart + 1 * NT + w) * (N2 * 8), smem + 1 * TILEB + w * ROWB, lane);

    tile_body<0>(xb, smem, outp, tid, lane, w, tstart, v, r);
    tile_body<1>(xb, smem, outp, tid, lane, w, tstart, v, r);
    tile_body<2>(xb, smem, outp, tid, lane, w, tstart, v, r);
    tile_body<3>(xb, smem, outp, tid, lane, w, tstart, v, r);
    tile_body<4>(xb, smem, outp, tid, lane, w, tstart, v, r);
    tile_body<5>(xb, smem, outp, tid, lane, w, tstart, v, r);
    tile_body<6>(xb, smem, outp, tid, lane, w, tstart, v, r);
    tile_body<7>(xb, smem, outp, tid, lane, w, tstart, v, r);
}

extern "C" void kernel_launch(void* const* d_in, const int* in_sizes, int n_in,
                              void* d_out, int out_size, void* d_ws, size_t ws_size,
                              hipStream_t stream) {
    const v2f* x = (const v2f*)d_in[0];
    v2f* out = (v2f*)d_out;
    // grid: 128 neuron-blocks x 16 time-chunks = 2048 blocks (8/CU,
    // 32 waves/CU; LDS 16 KiB/block caps at 10/CU — not binding).
    izi_kernel<<<dim3(N2 / 256, T_STEPS / TCH), dim3(256), 0, stream>>>(x, out);
}